// Round 1
// baseline (416.347 us; speedup 1.0000x reference)
//
#include <hip/hip_runtime.h>
#include <math.h>

#define HH   768
#define WW   1024
#define CC   128
#define HWN  (HH*WW)          // 786432
#define KTOP 5000
#define CAND_CAP 204800
#define SEL_CAP  8192
#define NBINS    4096
#define BIN_BASE 0x3E800u     // __float_as_uint(0.25f) >> 12

// ---- workspace layout (bytes) ----
// rep map   : [0, 3145728)
// smap      : [3145728, 6291456)     rel-gated score (rel>=0.7 ? rel*rep : -1)
// cand u64  : [6291456, +CAND_CAP*8)
// hist u32  : NBINS*4
// counters  : 64 bytes  (ctr[0]=cand_count, ctr[1]=sel_count, ctr[2]=thr_bits)
// sel u64   : SEL_CAP*8
// sorted u64: KTOP*8
#define OFF_REP    0ull
#define OFF_SMAP   3145728ull
#define OFF_CAND   6291456ull
#define OFF_HIST   (OFF_CAND + (unsigned long long)CAND_CAP*8ull)
#define OFF_CTR    (OFF_HIST + (unsigned long long)NBINS*4ull)
#define OFF_SEL    (OFF_CTR + 64ull)
#define OFF_SORTED (OFF_SEL + (unsigned long long)SEL_CAP*8ull)

// correctly-rounded f32 exp via f64
__device__ __forceinline__ float exp_cr(float x) {
    return (float)::exp((double)x);
}

__global__ void k_zero(unsigned* hist, unsigned* ctr) {
    int t = blockIdx.x * blockDim.x + threadIdx.x;
    if (t < NBINS) hist[t] = 0u;
    if (t < 16) ctr[t] = 0u;
}

// per-pixel heads: u_o = sum_c f^2 * w[c,o] (sequential FMA chain) + b, 2-way softmax ch1
__global__ void k_maps(const float* __restrict__ f,
                       const float* __restrict__ cw, const float* __restrict__ cb,
                       const float* __restrict__ sw, const float* __restrict__ sb,
                       float* __restrict__ rep, float* __restrict__ smap) {
    __shared__ float w0[CC], w1[CC], w2[CC], w3[CC];
    int t = threadIdx.x;
    for (int c = t; c < CC; c += blockDim.x) {
        w0[c] = cw[2*c];  w1[c] = cw[2*c+1];
        w2[c] = sw[2*c];  w3[c] = sw[2*c+1];
    }
    __syncthreads();
    int p = blockIdx.x * blockDim.x + t;
    if (p >= HWN) return;
    const float* fp = f + p;
    float a0 = 0.f, a1 = 0.f, a2 = 0.f, a3 = 0.f;
    for (int c = 0; c < CC; ++c) {
        float v  = fp[(long)c * HWN];
        float f2 = v * v;
        a0 = fmaf(f2, w0[c], a0);
        a1 = fmaf(f2, w1[c], a1);
        a2 = fmaf(f2, w2[c], a2);
        a3 = fmaf(f2, w3[c], a3);
    }
    float u0 = a0 + cb[0], u1 = a1 + cb[1];
    float v0 = a2 + sb[0], v1 = a3 + sb[1];

    float mr  = fmaxf(u0, u1);
    float er0 = exp_cr(u0 - mr);
    float er1 = exp_cr(u1 - mr);
    float rel = er1 / (er0 + er1);

    float mp  = fmaxf(v0, v1);
    float ep0 = exp_cr(v0 - mp);
    float ep1 = exp_cr(v1 - mp);
    float rp  = ep1 / (ep0 + ep1);

    rep[p]  = rp;
    smap[p] = (rel >= 0.7f) ? rel * rp : -1.0f;
}

// NMS: center >= all 8 neighbors (== maxpool3 equality), rep>=0.7, rel>=0.7
__global__ void k_nms(const float* __restrict__ rep, const float* __restrict__ smap,
                      unsigned long long* __restrict__ cand, unsigned* __restrict__ ctr) {
    int p = blockIdx.x * blockDim.x + threadIdx.x;
    if (p >= HWN) return;
    float r = rep[p];
    if (!(r >= 0.7f)) return;
    float s = smap[p];
    if (!(s >= 0.f)) return;
    int x = p & (WW - 1), y = p >> 10;
    float m = -INFINITY;
    if (y > 0) {
        const float* rr = rep + p - WW;
        if (x > 0)      m = fmaxf(m, rr[-1]);
        m = fmaxf(m, rr[0]);
        if (x < WW - 1) m = fmaxf(m, rr[1]);
    }
    if (x > 0)      m = fmaxf(m, rep[p - 1]);
    if (x < WW - 1) m = fmaxf(m, rep[p + 1]);
    if (y < HH - 1) {
        const float* rr = rep + p + WW;
        if (x > 0)      m = fmaxf(m, rr[-1]);
        m = fmaxf(m, rr[0]);
        if (x < WW - 1) m = fmaxf(m, rr[1]);
    }
    if (r < m) return;  // not the 3x3 max
    unsigned pos = atomicAdd(&ctr[0], 1u);
    if (pos < CAND_CAP) {
        unsigned sb = __float_as_uint(s);
        cand[pos] = ((unsigned long long)sb << 32) |
                    (unsigned long long)(0xFFFFFFFFu - (unsigned)p);
    }
}

__global__ void k_hist(const unsigned long long* __restrict__ cand,
                       const unsigned* __restrict__ ctr, unsigned* __restrict__ hist) {
    unsigned n = ctr[0]; if (n > CAND_CAP) n = CAND_CAP;
    int stride = gridDim.x * blockDim.x;
    for (unsigned i = blockIdx.x * blockDim.x + threadIdx.x; i < n; i += stride) {
        unsigned bits = (unsigned)(cand[i] >> 32);
        int bin = (int)(bits >> 12) - (int)BIN_BASE;
        bin = bin < 0 ? 0 : (bin > NBINS - 1 ? NBINS - 1 : bin);
        atomicAdd(&hist[bin], 1u);
    }
}

__global__ void k_thr(const unsigned* __restrict__ hist, unsigned* __restrict__ ctr) {
    if (threadIdx.x != 0 || blockIdx.x != 0) return;
    unsigned cum = 0; int b = NBINS - 1;
    for (; b >= 0; --b) { cum += hist[b]; if (cum >= KTOP) break; }
    unsigned thr = (b <= 0) ? 0u : ((unsigned)(b + (int)BIN_BASE) << 12);
    ctr[2] = thr;
}

__global__ void k_select(const unsigned long long* __restrict__ cand,
                         unsigned* __restrict__ ctr, unsigned long long* __restrict__ sel) {
    unsigned n = ctr[0]; if (n > CAND_CAP) n = CAND_CAP;
    unsigned thr = ctr[2];
    int stride = gridDim.x * blockDim.x;
    for (unsigned i = blockIdx.x * blockDim.x + threadIdx.x; i < n; i += stride) {
        unsigned long long k = cand[i];
        if ((unsigned)(k >> 32) >= thr) {
            unsigned pos = atomicAdd(&ctr[1], 1u);
            if (pos < SEL_CAP) sel[pos] = k;
        }
    }
}

// single-workgroup LDS bitonic sort, descending; key = (score_bits<<32)|(~idx)
__global__ __launch_bounds__(1024) void k_sort(const unsigned long long* __restrict__ sel,
                                               const unsigned* __restrict__ ctr,
                                               unsigned long long* __restrict__ sorted) {
    __shared__ unsigned long long buf[SEL_CAP];
    unsigned n = ctr[1]; if (n > SEL_CAP) n = SEL_CAP;
    for (int i = threadIdx.x; i < SEL_CAP; i += 1024)
        buf[i] = (i < (int)n) ? sel[i] : 0ull;
    __syncthreads();
    for (int k = 2; k <= SEL_CAP; k <<= 1) {
        for (int j = k >> 1; j >= 1; j >>= 1) {
            for (int i = threadIdx.x; i < SEL_CAP; i += 1024) {
                int ixj = i ^ j;
                if (ixj > i) {
                    unsigned long long a = buf[i], bv = buf[ixj];
                    bool desc = ((i & k) == 0);
                    if (desc ? (a < bv) : (a > bv)) { buf[i] = bv; buf[ixj] = a; }
                }
            }
            __syncthreads();
        }
    }
    for (int i = threadIdx.x; i < KTOP; i += 1024) sorted[i] = buf[i];
}

__global__ void k_emit(const unsigned long long* __restrict__ sorted, float* __restrict__ out) {
    int r = blockIdx.x * blockDim.x + threadIdx.x;
    if (r >= KTOP) return;
    unsigned long long key = sorted[r];
    unsigned sbits = (unsigned)(key >> 32);
    unsigned p = 0xFFFFFFFFu - (unsigned)(key & 0xFFFFFFFFull);
    if (p >= HWN) p = 0;
    int x = p & (WW - 1), y = p >> 10;
    out[2*r]     = (float)x;
    out[2*r + 1] = (float)y;
    out[2*KTOP + r] = __uint_as_float(sbits);
}

// one block per keypoint: gather 128 channels, L2-normalize
__global__ void k_desc(const float* __restrict__ f,
                       const unsigned long long* __restrict__ sorted, float* __restrict__ out) {
    int r = blockIdx.x;
    unsigned long long key = sorted[r];
    unsigned p = 0xFFFFFFFFu - (unsigned)(key & 0xFFFFFFFFull);
    if (p >= HWN) p = 0;
    int c = threadIdx.x;
    float v = f[(long)c * HWN + p];
    float ss = v * v;
    for (int o = 32; o > 0; o >>= 1) ss += __shfl_down(ss, o);
    __shared__ float partial[2];
    if ((c & 63) == 0) partial[c >> 6] = ss;
    __syncthreads();
    float tot = partial[0] + partial[1];
    float nm = fmaxf(sqrtf(tot), 1e-12f);
    out[3*KTOP + (long)r*CC + c] = v / nm;
}

extern "C" void kernel_launch(void* const* d_in, const int* in_sizes, int n_in,
                              void* d_out, int out_size, void* d_ws, size_t ws_size,
                              hipStream_t stream) {
    const float* feat = (const float*)d_in[0];
    const float* cw   = (const float*)d_in[1];
    const float* cb   = (const float*)d_in[2];
    const float* sw   = (const float*)d_in[3];
    const float* sb   = (const float*)d_in[4];
    float* out = (float*)d_out;

    char* ws = (char*)d_ws;
    float* rep  = (float*)(ws + OFF_REP);
    float* smap = (float*)(ws + OFF_SMAP);
    unsigned long long* cand   = (unsigned long long*)(ws + OFF_CAND);
    unsigned* hist             = (unsigned*)(ws + OFF_HIST);
    unsigned* ctr              = (unsigned*)(ws + OFF_CTR);
    unsigned long long* sel    = (unsigned long long*)(ws + OFF_SEL);
    unsigned long long* sorted = (unsigned long long*)(ws + OFF_SORTED);

    k_zero<<<dim3((NBINS + 255) / 256), dim3(256), 0, stream>>>(hist, ctr);
    k_maps<<<dim3(HWN / 256), dim3(256), 0, stream>>>(feat, cw, cb, sw, sb, rep, smap);
    k_nms<<<dim3(HWN / 256), dim3(256), 0, stream>>>(rep, smap, cand, ctr);
    k_hist<<<dim3(512), dim3(256), 0, stream>>>(cand, ctr, hist);
    k_thr<<<dim3(1), dim3(64), 0, stream>>>(hist, ctr);
    k_select<<<dim3(512), dim3(256), 0, stream>>>(cand, ctr, sel);
    k_sort<<<dim3(1), dim3(1024), 0, stream>>>(sel, ctr, sorted);
    k_emit<<<dim3((KTOP + 255) / 256), dim3(256), 0, stream>>>(sorted, out);
    k_desc<<<dim3(KTOP), dim3(CC), 0, stream>>>(feat, sorted, out);
}

// Round 2
// 289.822 us; speedup vs baseline: 1.4366x; 1.4366x over previous
//
#include <hip/hip_runtime.h>
#include <math.h>

#define HH   768
#define WW   1024
#define CC   128
#define HWN  (HH*WW)          // 786432
#define KTOP 5000
#define CAND_CAP 204800
#define SEL_CAP  8192
#define NBINS    4096
#define BIN_BASE 0x3E800u     // __float_as_uint(0.25f) >> 12

// ---- workspace layout (bytes) ----
#define OFF_REP    0ull
#define OFF_SMAP   3145728ull
#define OFF_CAND   6291456ull
#define OFF_HIST   (OFF_CAND + (unsigned long long)CAND_CAP*8ull)
#define OFF_CTR    (OFF_HIST + (unsigned long long)NBINS*4ull)
#define OFF_SEL    (OFF_CTR + 64ull)
#define OFF_SORTED (OFF_SEL + (unsigned long long)SEL_CAP*8ull)

// correctly-rounded f32 exp via f64 (matches reference rounding; verified R1)
__device__ __forceinline__ float exp_cr(float x) {
    return (float)::exp((double)x);
}

__global__ void k_zero(unsigned* hist, unsigned* ctr, unsigned* sorted32) {
    int t = blockIdx.x * blockDim.x + threadIdx.x;
    if (t < NBINS) hist[t] = 0u;
    if (t < 16) ctr[t] = 0u;
    if (t < KTOP * 2) sorted32[t] = 0u;   // zero-fill sorted (tail determinism)
}

// per-pixel heads, 4 pixels/thread via float4; per-pixel FMA chain identical to R1
__global__ __launch_bounds__(256) void k_maps(const float* __restrict__ f,
                       const float* __restrict__ cw, const float* __restrict__ cb,
                       const float* __restrict__ sw, const float* __restrict__ sb,
                       float* __restrict__ rep, float* __restrict__ smap) {
    __shared__ float w0[CC], w1[CC], w2[CC], w3[CC];
    int t = threadIdx.x;
    if (t < CC) {
        w0[t] = cw[2*t];  w1[t] = cw[2*t+1];
        w2[t] = sw[2*t];  w3[t] = sw[2*t+1];
    }
    __syncthreads();
    int p0 = (blockIdx.x * blockDim.x + t) * 4;
    if (p0 >= HWN) return;
    const float4* fp = (const float4*)(f + p0);   // 16B aligned: p0%4==0, HWN%4==0
    float a0[4] = {0,0,0,0}, a1[4] = {0,0,0,0}, a2[4] = {0,0,0,0}, a3[4] = {0,0,0,0};
    for (int c = 0; c < CC; ++c) {
        float4 v = fp[(long)c * (HWN/4)];
        float vv[4] = {v.x, v.y, v.z, v.w};
        float W0 = w0[c], W1 = w1[c], W2 = w2[c], W3 = w3[c];
        #pragma unroll
        for (int j = 0; j < 4; ++j) {
            float f2 = vv[j] * vv[j];
            a0[j] = fmaf(f2, W0, a0[j]);
            a1[j] = fmaf(f2, W1, a1[j]);
            a2[j] = fmaf(f2, W2, a2[j]);
            a3[j] = fmaf(f2, W3, a3[j]);
        }
    }
    float cb0 = cb[0], cb1 = cb[1], sb0 = sb[0], sb1 = sb[1];
    float rp4[4], sm4[4];
    #pragma unroll
    for (int j = 0; j < 4; ++j) {
        float u0 = a0[j] + cb0, u1 = a1[j] + cb1;
        float v0 = a2[j] + sb0, v1 = a3[j] + sb1;
        float mr  = fmaxf(u0, u1);
        float er0 = exp_cr(u0 - mr);
        float er1 = exp_cr(u1 - mr);
        float rel = er1 / (er0 + er1);
        float mp  = fmaxf(v0, v1);
        float ep0 = exp_cr(v0 - mp);
        float ep1 = exp_cr(v1 - mp);
        float rp  = ep1 / (ep0 + ep1);
        rp4[j] = rp;
        sm4[j] = (rel >= 0.7f) ? rel * rp : -1.0f;
    }
    *(float4*)(rep + p0)  = make_float4(rp4[0], rp4[1], rp4[2], rp4[3]);
    *(float4*)(smap + p0) = make_float4(sm4[0], sm4[1], sm4[2], sm4[3]);
}

// NMS + fused histogram: center >= all 8 neighbors, rep>=0.7, rel>=0.7
__global__ void k_nms(const float* __restrict__ rep, const float* __restrict__ smap,
                      unsigned long long* __restrict__ cand, unsigned* __restrict__ ctr,
                      unsigned* __restrict__ hist) {
    int p = blockIdx.x * blockDim.x + threadIdx.x;
    if (p >= HWN) return;
    float r = rep[p];
    if (!(r >= 0.7f)) return;
    float s = smap[p];
    if (!(s >= 0.f)) return;
    int x = p & (WW - 1), y = p >> 10;
    float m = -INFINITY;
    if (y > 0) {
        const float* rr = rep + p - WW;
        if (x > 0)      m = fmaxf(m, rr[-1]);
        m = fmaxf(m, rr[0]);
        if (x < WW - 1) m = fmaxf(m, rr[1]);
    }
    if (x > 0)      m = fmaxf(m, rep[p - 1]);
    if (x < WW - 1) m = fmaxf(m, rep[p + 1]);
    if (y < HH - 1) {
        const float* rr = rep + p + WW;
        if (x > 0)      m = fmaxf(m, rr[-1]);
        m = fmaxf(m, rr[0]);
        if (x < WW - 1) m = fmaxf(m, rr[1]);
    }
    if (r < m) return;
    unsigned pos = atomicAdd(&ctr[0], 1u);
    if (pos < CAND_CAP) {
        unsigned sb = __float_as_uint(s);
        cand[pos] = ((unsigned long long)sb << 32) |
                    (unsigned long long)(0xFFFFFFFFu - (unsigned)p);
        int bin = (int)(sb >> 12) - (int)BIN_BASE;
        bin = bin < 0 ? 0 : (bin > NBINS - 1 ? NBINS - 1 : bin);
        atomicAdd(&hist[bin], 1u);
    }
}

// parallel threshold-bin search: suffix-scan of 4096 bins with 1024 threads
__global__ __launch_bounds__(1024) void k_thr(const unsigned* __restrict__ hist,
                                              unsigned* __restrict__ ctr) {
    __shared__ unsigned ps[1024];
    __shared__ int best;
    int t = threadIdx.x;
    if (t == 0) best = -1;
    unsigned h[4];
    unsigned s = 0;
    #pragma unroll
    for (int k = 0; k < 4; ++k) { h[k] = hist[t*4 + k]; s += h[k]; }
    ps[t] = s;
    __syncthreads();
    for (int off = 1; off < 1024; off <<= 1) {
        unsigned v = (t + off < 1024) ? ps[t + off] : 0u;
        __syncthreads();
        ps[t] += v;
        __syncthreads();
    }
    // ps[t] = sum of bins >= 4t
    unsigned above4 = (t < 1023) ? ps[t + 1] : 0u;
    int local = -1;
    unsigned cum = above4;
    #pragma unroll
    for (int k = 3; k >= 0; --k) {
        cum += h[k];
        if (local < 0 && cum >= KTOP) local = t*4 + k;
    }
    if (local >= 0) atomicMax(&best, local);
    __syncthreads();
    if (t == 0) {
        int b = best;
        ctr[2] = (b <= 0) ? 0u : ((unsigned)(b + (int)BIN_BASE) << 12);
    }
}

__global__ void k_select(const unsigned long long* __restrict__ cand,
                         unsigned* __restrict__ ctr, unsigned long long* __restrict__ sel) {
    unsigned n = ctr[0]; if (n > CAND_CAP) n = CAND_CAP;
    unsigned thr = ctr[2];
    int stride = gridDim.x * blockDim.x;
    for (unsigned i = blockIdx.x * blockDim.x + threadIdx.x; i < n; i += stride) {
        unsigned long long k = cand[i];
        if ((unsigned)(k >> 32) >= thr) {
            unsigned pos = atomicAdd(&ctr[1], 1u);
            if (pos < SEL_CAP) sel[pos] = k;
        }
    }
}

// exact-rank placement: keys unique -> rank = #{keys > mine}; one wave per 8 entries
__global__ __launch_bounds__(256) void k_rank(const unsigned long long* __restrict__ sel,
                                              const unsigned* __restrict__ ctr,
                                              unsigned long long* __restrict__ sorted) {
    unsigned n = ctr[1]; if (n > SEL_CAP) n = SEL_CAP;
    int wave = (blockIdx.x * 256 + threadIdx.x) >> 6;   // 0..1023
    int lane = threadIdx.x & 63;
    int base = wave * 8;
    if (base >= (int)n) return;
    unsigned long long my[8];
    unsigned cnt[8] = {0,0,0,0,0,0,0,0};
    #pragma unroll
    for (int e = 0; e < 8; ++e)
        my[e] = (base + e < (int)n) ? sel[base + e] : ~0ull;
    for (int j = lane; j < (int)n; j += 64) {
        unsigned long long k = sel[j];
        #pragma unroll
        for (int e = 0; e < 8; ++e) cnt[e] += (k > my[e]) ? 1u : 0u;
    }
    #pragma unroll
    for (int e = 0; e < 8; ++e) {
        unsigned c = cnt[e];
        for (int o = 32; o > 0; o >>= 1) c += __shfl_xor(c, o);
        if (lane == 0 && base + e < (int)n && c < KTOP) sorted[c] = my[e];
    }
}

__global__ void k_emit(const unsigned long long* __restrict__ sorted, float* __restrict__ out) {
    int r = blockIdx.x * blockDim.x + threadIdx.x;
    if (r >= KTOP) return;
    unsigned long long key = sorted[r];
    unsigned sbits = (unsigned)(key >> 32);
    unsigned p = 0xFFFFFFFFu - (unsigned)(key & 0xFFFFFFFFull);
    if (p >= HWN) p = 0;
    int x = p & (WW - 1), y = p >> 10;
    out[2*r]     = (float)x;
    out[2*r + 1] = (float)y;
    out[2*KTOP + r] = __uint_as_float(sbits);
}

// one block per keypoint: gather 128 channels, L2-normalize
__global__ void k_desc(const float* __restrict__ f,
                       const unsigned long long* __restrict__ sorted, float* __restrict__ out) {
    int r = blockIdx.x;
    unsigned long long key = sorted[r];
    unsigned p = 0xFFFFFFFFu - (unsigned)(key & 0xFFFFFFFFull);
    if (p >= HWN) p = 0;
    int c = threadIdx.x;
    float v = f[(long)c * HWN + p];
    float ss = v * v;
    for (int o = 32; o > 0; o >>= 1) ss += __shfl_down(ss, o);
    __shared__ float partial[2];
    if ((c & 63) == 0) partial[c >> 6] = ss;
    __syncthreads();
    float tot = partial[0] + partial[1];
    float nm = fmaxf(sqrtf(tot), 1e-12f);
    out[3*KTOP + (long)r*CC + c] = v / nm;
}

extern "C" void kernel_launch(void* const* d_in, const int* in_sizes, int n_in,
                              void* d_out, int out_size, void* d_ws, size_t ws_size,
                              hipStream_t stream) {
    const float* feat = (const float*)d_in[0];
    const float* cw   = (const float*)d_in[1];
    const float* cb   = (const float*)d_in[2];
    const float* sw   = (const float*)d_in[3];
    const float* sb   = (const float*)d_in[4];
    float* out = (float*)d_out;

    char* ws = (char*)d_ws;
    float* rep  = (float*)(ws + OFF_REP);
    float* smap = (float*)(ws + OFF_SMAP);
    unsigned long long* cand   = (unsigned long long*)(ws + OFF_CAND);
    unsigned* hist             = (unsigned*)(ws + OFF_HIST);
    unsigned* ctr              = (unsigned*)(ws + OFF_CTR);
    unsigned long long* sel    = (unsigned long long*)(ws + OFF_SEL);
    unsigned long long* sorted = (unsigned long long*)(ws + OFF_SORTED);

    k_zero<<<dim3(64), dim3(256), 0, stream>>>(hist, ctr, (unsigned*)sorted);
    k_maps<<<dim3(HWN / 1024), dim3(256), 0, stream>>>(feat, cw, cb, sw, sb, rep, smap);
    k_nms<<<dim3(HWN / 256), dim3(256), 0, stream>>>(rep, smap, cand, ctr, hist);
    k_thr<<<dim3(1), dim3(1024), 0, stream>>>(hist, ctr);
    k_select<<<dim3(512), dim3(256), 0, stream>>>(cand, ctr, sel);
    k_rank<<<dim3(256), dim3(256), 0, stream>>>(sel, ctr, sorted);
    k_emit<<<dim3((KTOP + 255) / 256), dim3(256), 0, stream>>>(sorted, out);
    k_desc<<<dim3(KTOP), dim3(CC), 0, stream>>>(feat, sorted, out);
}

// Round 3
// 287.867 us; speedup vs baseline: 1.4463x; 1.0068x over previous
//
#include <hip/hip_runtime.h>
#include <math.h>

#define HH   768
#define WW   1024
#define CC   128
#define HWN  (HH*WW)          // 786432
#define KTOP 5000
#define CAND_CAP 204800
#define SEL_CAP  8192
#define NBINS    4096
#define BIN_BASE 0x3E800u     // __float_as_uint(0.25f) >> 12

// ---- workspace layout (bytes) ----
#define OFF_REP    0ull
#define OFF_SMAP   3145728ull
#define OFF_CAND   6291456ull
#define OFF_HIST   (OFF_CAND + (unsigned long long)CAND_CAP*8ull)
#define OFF_CTR    (OFF_HIST + (unsigned long long)NBINS*4ull)
#define OFF_SEL    (OFF_CTR + 64ull)
#define OFF_SORTED (OFF_SEL + (unsigned long long)SEL_CAP*8ull)

// correctly-rounded f32 exp via f64 (matches reference rounding; verified R1/R2)
__device__ __forceinline__ float exp_cr(float x) {
    return (float)::exp((double)x);
}

__global__ void k_zero(unsigned* hist, unsigned* ctr, unsigned* sorted32) {
    int t = blockIdx.x * blockDim.x + threadIdx.x;
    if (t < NBINS) hist[t] = 0u;
    if (t < 16) ctr[t] = 0u;
    if (t < KTOP * 2) sorted32[t] = 0u;   // tail determinism if <KTOP selected
}

// per-pixel heads, 4 px/thread via float4, software-pipelined channel loads.
// FMA accumulation order per pixel is EXACTLY c=0..127 sequential (bit-exact vs R1/R2).
__global__ __launch_bounds__(256, 4) void k_maps(const float* __restrict__ f,
                       const float* __restrict__ cw, const float* __restrict__ cb,
                       const float* __restrict__ sw, const float* __restrict__ sb,
                       float* __restrict__ rep, float* __restrict__ smap) {
    __shared__ float w0[CC], w1[CC], w2[CC], w3[CC];
    int t = threadIdx.x;
    if (t < CC) {
        w0[t] = cw[2*t];  w1[t] = cw[2*t+1];
        w2[t] = sw[2*t];  w3[t] = sw[2*t+1];
    }
    __syncthreads();
    int p0 = (blockIdx.x * blockDim.x + t) * 4;
    if (p0 >= HWN) return;
    const float4* fp = (const float4*)(f + p0);
    const long step = HWN / 4;

    float a0[4] = {0,0,0,0}, a1[4] = {0,0,0,0}, a2[4] = {0,0,0,0}, a3[4] = {0,0,0,0};
    float4 A[4], B[4];
    #pragma unroll
    for (int k = 0; k < 4; ++k) A[k] = fp[(long)k * step];

    #define FMA4(REG, CBASE)                                             \
        _Pragma("unroll")                                                \
        for (int k = 0; k < 4; ++k) {                                    \
            int c = (CBASE) + k;                                         \
            float W0 = w0[c], W1 = w1[c], W2 = w2[c], W3 = w3[c];        \
            float vv[4] = {REG[k].x, REG[k].y, REG[k].z, REG[k].w};      \
            _Pragma("unroll")                                            \
            for (int j = 0; j < 4; ++j) {                                \
                float f2 = vv[j] * vv[j];                                \
                a0[j] = fmaf(f2, W0, a0[j]);                             \
                a1[j] = fmaf(f2, W1, a1[j]);                             \
                a2[j] = fmaf(f2, W2, a2[j]);                             \
                a3[j] = fmaf(f2, W3, a3[j]);                             \
            }                                                            \
        }

    for (int c0 = 0; c0 < CC; c0 += 8) {
        #pragma unroll
        for (int k = 0; k < 4; ++k) B[k] = fp[(long)(c0 + 4 + k) * step];  // prefetch c0+4..7
        FMA4(A, c0)
        if (c0 + 8 < CC) {
            #pragma unroll
            for (int k = 0; k < 4; ++k) A[k] = fp[(long)(c0 + 8 + k) * step];  // prefetch c0+8..11
        }
        FMA4(B, c0 + 4)
    }
    #undef FMA4

    float cb0 = cb[0], cb1 = cb[1], sb0 = sb[0], sb1 = sb[1];
    float rp4[4], sm4[4];
    #pragma unroll
    for (int j = 0; j < 4; ++j) {
        float u0 = a0[j] + cb0, u1 = a1[j] + cb1;
        float v0 = a2[j] + sb0, v1 = a3[j] + sb1;
        float mr  = fmaxf(u0, u1);
        float er0 = exp_cr(u0 - mr);
        float er1 = exp_cr(u1 - mr);
        float rel = er1 / (er0 + er1);
        float mp  = fmaxf(v0, v1);
        float ep0 = exp_cr(v0 - mp);
        float ep1 = exp_cr(v1 - mp);
        float rp  = ep1 / (ep0 + ep1);
        rp4[j] = rp;
        sm4[j] = (rel >= 0.7f) ? rel * rp : -1.0f;
    }
    *(float4*)(rep + p0)  = make_float4(rp4[0], rp4[1], rp4[2], rp4[3]);
    *(float4*)(smap + p0) = make_float4(sm4[0], sm4[1], sm4[2], sm4[3]);
}

// NMS + fused histogram: center >= all 8 neighbors, rep>=0.7, rel>=0.7
__global__ void k_nms(const float* __restrict__ rep, const float* __restrict__ smap,
                      unsigned long long* __restrict__ cand, unsigned* __restrict__ ctr,
                      unsigned* __restrict__ hist) {
    int p = blockIdx.x * blockDim.x + threadIdx.x;
    if (p >= HWN) return;
    float r = rep[p];
    if (!(r >= 0.7f)) return;
    float s = smap[p];
    if (!(s >= 0.f)) return;
    int x = p & (WW - 1), y = p >> 10;
    float m = -INFINITY;
    if (y > 0) {
        const float* rr = rep + p - WW;
        if (x > 0)      m = fmaxf(m, rr[-1]);
        m = fmaxf(m, rr[0]);
        if (x < WW - 1) m = fmaxf(m, rr[1]);
    }
    if (x > 0)      m = fmaxf(m, rep[p - 1]);
    if (x < WW - 1) m = fmaxf(m, rep[p + 1]);
    if (y < HH - 1) {
        const float* rr = rep + p + WW;
        if (x > 0)      m = fmaxf(m, rr[-1]);
        m = fmaxf(m, rr[0]);
        if (x < WW - 1) m = fmaxf(m, rr[1]);
    }
    if (r < m) return;
    unsigned pos = atomicAdd(&ctr[0], 1u);
    if (pos < CAND_CAP) {
        unsigned sb = __float_as_uint(s);
        cand[pos] = ((unsigned long long)sb << 32) |
                    (unsigned long long)(0xFFFFFFFFu - (unsigned)p);
        int bin = (int)(sb >> 12) - (int)BIN_BASE;
        bin = bin < 0 ? 0 : (bin > NBINS - 1 ? NBINS - 1 : bin);
        atomicAdd(&hist[bin], 1u);
    }
}

// parallel threshold-bin search: suffix-scan of 4096 bins with 1024 threads
__global__ __launch_bounds__(1024) void k_thr(const unsigned* __restrict__ hist,
                                              unsigned* __restrict__ ctr) {
    __shared__ unsigned ps[1024];
    __shared__ int best;
    int t = threadIdx.x;
    if (t == 0) best = -1;
    unsigned h[4];
    unsigned s = 0;
    #pragma unroll
    for (int k = 0; k < 4; ++k) { h[k] = hist[t*4 + k]; s += h[k]; }
    ps[t] = s;
    __syncthreads();
    for (int off = 1; off < 1024; off <<= 1) {
        unsigned v = (t + off < 1024) ? ps[t + off] : 0u;
        __syncthreads();
        ps[t] += v;
        __syncthreads();
    }
    unsigned above4 = (t < 1023) ? ps[t + 1] : 0u;
    int local = -1;
    unsigned cum = above4;
    #pragma unroll
    for (int k = 3; k >= 0; --k) {
        cum += h[k];
        if (local < 0 && cum >= KTOP) local = t*4 + k;
    }
    if (local >= 0) atomicMax(&best, local);
    __syncthreads();
    if (t == 0) {
        int b = best;
        ctr[2] = (b <= 0) ? 0u : ((unsigned)(b + (int)BIN_BASE) << 12);
    }
}

__global__ void k_select(const unsigned long long* __restrict__ cand,
                         unsigned* __restrict__ ctr, unsigned long long* __restrict__ sel) {
    unsigned n = ctr[0]; if (n > CAND_CAP) n = CAND_CAP;
    unsigned thr = ctr[2];
    int stride = gridDim.x * blockDim.x;
    for (unsigned i = blockIdx.x * blockDim.x + threadIdx.x; i < n; i += stride) {
        unsigned long long k = cand[i];
        if ((unsigned)(k >> 32) >= thr) {
            unsigned pos = atomicAdd(&ctr[1], 1u);
            if (pos < SEL_CAP) sel[pos] = k;
        }
    }
}

// exact-rank placement: keys unique -> rank = #{keys > mine}; one wave per 8 entries
__global__ __launch_bounds__(256) void k_rank(const unsigned long long* __restrict__ sel,
                                              const unsigned* __restrict__ ctr,
                                              unsigned long long* __restrict__ sorted) {
    unsigned n = ctr[1]; if (n > SEL_CAP) n = SEL_CAP;
    int wave = (blockIdx.x * 256 + threadIdx.x) >> 6;
    int lane = threadIdx.x & 63;
    int base = wave * 8;
    if (base >= (int)n) return;
    unsigned long long my[8];
    unsigned cnt[8] = {0,0,0,0,0,0,0,0};
    #pragma unroll
    for (int e = 0; e < 8; ++e)
        my[e] = (base + e < (int)n) ? sel[base + e] : ~0ull;
    for (int j = lane; j < (int)n; j += 64) {
        unsigned long long k = sel[j];
        #pragma unroll
        for (int e = 0; e < 8; ++e) cnt[e] += (k > my[e]) ? 1u : 0u;
    }
    #pragma unroll
    for (int e = 0; e < 8; ++e) {
        unsigned c = cnt[e];
        for (int o = 32; o > 0; o >>= 1) c += __shfl_xor(c, o);
        if (lane == 0 && base + e < (int)n && c < KTOP) sorted[c] = my[e];
    }
}

// 2 keypoints per 256-thread block: emit kp/score + gather 128 channels, L2-normalize
__global__ __launch_bounds__(256) void k_desc(const float* __restrict__ f,
                       const unsigned long long* __restrict__ sorted, float* __restrict__ out) {
    __shared__ float partial[4];
    int half = threadIdx.x >> 7;            // 0 or 1
    int r = blockIdx.x * 2 + half;
    int c = threadIdx.x & 127;
    if (r >= KTOP) return;
    unsigned long long key = sorted[r];
    unsigned sbits = (unsigned)(key >> 32);
    unsigned p = 0xFFFFFFFFu - (unsigned)(key & 0xFFFFFFFFull);
    if (p >= HWN) p = 0;
    if (c == 0) {
        int x = p & (WW - 1), y = p >> 10;
        out[2*r]        = (float)x;
        out[2*r + 1]    = (float)y;
        out[2*KTOP + r] = __uint_as_float(sbits);
    }
    float v = f[(long)c * HWN + p];
    float ss = v * v;
    for (int o = 32; o > 0; o >>= 1) ss += __shfl_down(ss, o);
    int w = threadIdx.x >> 6;               // wave id 0..3
    if ((threadIdx.x & 63) == 0) partial[w] = ss;
    __syncthreads();
    float tot = partial[half*2] + partial[half*2 + 1];
    float nm = fmaxf(sqrtf(tot), 1e-12f);
    out[3*KTOP + (long)r*CC + c] = v / nm;
}

extern "C" void kernel_launch(void* const* d_in, const int* in_sizes, int n_in,
                              void* d_out, int out_size, void* d_ws, size_t ws_size,
                              hipStream_t stream) {
    const float* feat = (const float*)d_in[0];
    const float* cw   = (const float*)d_in[1];
    const float* cb   = (const float*)d_in[2];
    const float* sw   = (const float*)d_in[3];
    const float* sb   = (const float*)d_in[4];
    float* out = (float*)d_out;

    char* ws = (char*)d_ws;
    float* rep  = (float*)(ws + OFF_REP);
    float* smap = (float*)(ws + OFF_SMAP);
    unsigned long long* cand   = (unsigned long long*)(ws + OFF_CAND);
    unsigned* hist             = (unsigned*)(ws + OFF_HIST);
    unsigned* ctr              = (unsigned*)(ws + OFF_CTR);
    unsigned long long* sel    = (unsigned long long*)(ws + OFF_SEL);
    unsigned long long* sorted = (unsigned long long*)(ws + OFF_SORTED);

    k_zero<<<dim3(64), dim3(256), 0, stream>>>(hist, ctr, (unsigned*)sorted);
    k_maps<<<dim3(HWN / 1024), dim3(256), 0, stream>>>(feat, cw, cb, sw, sb, rep, smap);
    k_nms<<<dim3(HWN / 256), dim3(256), 0, stream>>>(rep, smap, cand, ctr, hist);
    k_thr<<<dim3(1), dim3(1024), 0, stream>>>(hist, ctr);
    k_select<<<dim3(512), dim3(256), 0, stream>>>(cand, ctr, sel);
    k_rank<<<dim3(256), dim3(256), 0, stream>>>(sel, ctr, sorted);
    k_desc<<<dim3((KTOP + 1) / 2), dim3(256), 0, stream>>>(feat, sorted, out);
}